// Round 9
// baseline (733.466 us; speedup 1.0000x reference)
//
#include <hip/hip_runtime.h>
#include <cstdint>

#define B_ 64
#define N_ 512
#define D_ 256
#define L_ 4

typedef __bf16 bf16;
typedef __attribute__((ext_vector_type(8))) __bf16 bf16x8;
typedef __attribute__((ext_vector_type(4))) __bf16 bf16x4;
typedef __attribute__((ext_vector_type(4))) float f32x4;

#define MFMA16(a, b, c) __builtin_amdgcn_mfma_f32_16x16x32_bf16((a), (b), (c), 0, 0, 0)

__device__ __forceinline__ float sigmoidf_(float z) {
  return 1.0f / (1.0f + __expf(-z));
}

// ===========================================================================
// R9: line-capacity model (time ~ lines/CU * 9.4cy, validated on R6+R8) says
// halve block count again: 128-ROW strips, grid 256 = 1 block/CU, single
// dispatch wave. P[128][512] kept in REGISTERS during p1 (128 f32/thread);
// P halves parked in the two 67.6KB LDS buffers (P_a->bufB, P_b->bufA after
// q dies) so p3 streams xT ONCE against both halves. p0's A is LDS-staged
// (removes 8x redundant per-wave A loads). LDS 144.5KB.
// Packed unit u: lane L holds src[r16*16+(L&15)][kc*32+(L>>4)*8+e], e=0..7;
// valid as both MFMA A- and B-fragment. xbpk: [b][n/16][d/32] KCS=8.
// xTpk: [b][d/16][n/32] KCS=16. W: [col/16][k/32] KCS=8.
// ===========================================================================

#define UIDX(u) (((size_t)(u)) * 64 + lane)

__global__ __launch_bounds__(256) void pack_w(
    const float* __restrict__ src, bf16* __restrict__ dst)
{
  const int tid = threadIdx.x, lane = tid & 63;
  const int U = blockIdx.x * 4 + (tid >> 6);
  const int m = U >> 7, u = U & 127;
  const int r16 = u >> 3, kc = u & 7;
  const int row = r16 * 16 + (lane & 15);
  const int k0 = kc * 32 + (lane >> 4) * 8;
  const float* s = src + (size_t)m * D_ * D_ + (size_t)row * D_ + k0;
  const float4 v0 = *(const float4*)s;
  const float4 v1 = *(const float4*)(s + 4);
  bf16x8 o;
  o[0] = (bf16)v0.x; o[1] = (bf16)v0.y; o[2] = (bf16)v0.z; o[3] = (bf16)v0.w;
  o[4] = (bf16)v1.x; o[5] = (bf16)v1.y; o[6] = (bf16)v1.z; o[7] = (bf16)v1.w;
  ((bf16x8*)dst)[(size_t)U * 64 + lane] = o;
}

__global__ __launch_bounds__(256) void init_pack(
    const float* __restrict__ x, bf16* __restrict__ xbpk, bf16* __restrict__ xTpk)
{
  const int tid = threadIdx.x, lane = tid & 63;
  const int U = blockIdx.x * 4 + (tid >> 6);    // 0..32767
  const int b = U >> 9, u = U & 511;
  if (u < 256) {            // xbpk unit: r16 = n/16, kc = d/32
    const int n = (u >> 3) * 16 + (lane & 15);
    const int d = (u & 7) * 32 + (lane >> 4) * 8;
    const float* s = x + ((size_t)(b * N_ + n)) * D_ + d;
    const float4 v0 = *(const float4*)s;
    const float4 v1 = *(const float4*)(s + 4);
    bf16x8 o;
    o[0] = (bf16)v0.x; o[1] = (bf16)v0.y; o[2] = (bf16)v0.z; o[3] = (bf16)v0.w;
    o[4] = (bf16)v1.x; o[5] = (bf16)v1.y; o[6] = (bf16)v1.z; o[7] = (bf16)v1.w;
    ((bf16x8*)xbpk)[((size_t)b * 256 + u) * 64 + lane] = o;
  } else {                  // xTpk unit: r16 = d/16, kc = n/32
    const int u2 = u - 256;
    const int d = (u2 >> 4) * 16 + (lane & 15);
    const int n = (u2 & 15) * 32 + (lane >> 4) * 8;
    bf16x8 o;
#pragma unroll
    for (int e = 0; e < 8; ++e)
      o[e] = (bf16)x[((size_t)(b * N_ + n + e)) * D_ + d];
    ((bf16x8*)xTpk)[((size_t)b * 256 + u2) * 64 + lane] = o;
  }
}

// ---------------------------------------------------------------------------
// gat_layer: one block per (128-row strip, batch); 512 threads (8 waves);
// grid 256 = 1 block/CU exactly (one dispatch wave). LDS 144.5 KB.
// bufA: q -> P_b(stride 520) -> x'(264) -> resid/out(264)
// bufB: staged-A units -> P_a(stride 520) -> h(264)
// ---------------------------------------------------------------------------
__global__ __launch_bounds__(512, 1) void gat_layer(
    const bf16* __restrict__ xbpk_in, const bf16* __restrict__ xTpk_in,
    bf16* __restrict__ xbpk_out, bf16* __restrict__ xTpk_out,
    const bf16* __restrict__ Wap, const float* __restrict__ ba,
    const bf16* __restrict__ W0p, const float* __restrict__ b0,
    const bf16* __restrict__ W1p, const float* __restrict__ b1,
    const float* __restrict__ adj, const unsigned short* __restrict__ bits_in,
    unsigned short* __restrict__ bits_out, float* __restrict__ outA)
{
  __shared__ bf16 bufA[128 * 264];       // 67.6 KB
  __shared__ bf16 bufB[128 * 264];       // 67.6 KB
  __shared__ float psum[8][128];         // 4 KB
  __shared__ float rinvs[128];           // 0.5 KB
  __shared__ unsigned int bits_s[2048];  // 128 rows x 32 u16 = 8 KB

  const int tid = threadIdx.x, w = tid >> 6, lane = tid & 63;
  const int l16 = lane & 15, quad = lane >> 4;
  const int wg = blockIdx.x;
  const int lid = (wg & 7) * 32 + (wg >> 3);   // bijective XCD swizzle
  const int b = lid >> 2;                      // 4 strips per batch
  const int row0 = (lid & 3) * 128;

  const bf16x8* Xbp = (const bf16x8*)xbpk_in + (size_t)b * 16384;
  const bf16x8* Xtp = (const bf16x8*)xTpk_in + (size_t)b * 16384;
  bf16x8* XbpO = (bf16x8*)xbpk_out + (size_t)b * 16384;
  bf16x8* XtpO = (bf16x8*)xTpk_out + (size_t)b * 16384;
  const bf16x8* Wa8 = (const bf16x8*)Wap;
  const bf16x8* W08 = (const bf16x8*)W0p;
  const bf16x8* W18 = (const bf16x8*)W1p;

  if (bits_in) {
#pragma unroll
    for (int e = 0; e < 4; ++e) {
      const int t = tid + e * 512;
      bits_s[t] = ((const unsigned int*)bits_in)[((size_t)b * N_ + row0) * 16 + t];
    }
  }

  // ---- p0: stage A units cooperatively -> bufB; q = x@Wa^T+ba -> bufA ----
  {
#pragma unroll
    for (int j = 0; j < 8; ++j) {
      const int uu = w * 8 + j;                // 64 units = 64 KB (A strip)
      const bf16x8 v = Xbp[UIDX(((row0 >> 4) + (uu >> 3)) * 8 + (uu & 7))];
      *(bf16x8*)&bufB[uu * 512 + lane * 8] = v;
    }
    __syncthreads();
    f32x4 acc0[8][2] = {};
#pragma unroll
    for (int ks = 0; ks < 8; ++ks) {
      bf16x8 bw[2];
#pragma unroll
      for (int i = 0; i < 2; ++i)
        bw[i] = Wa8[UIDX((2 * w + i) * 8 + ks)];
#pragma unroll
      for (int m = 0; m < 8; ++m) {
        const bf16x8 af = *(const bf16x8*)&bufB[(m * 8 + ks) * 512 + lane * 8];
#pragma unroll
        for (int i = 0; i < 2; ++i) acc0[m][i] = MFMA16(af, bw[i], acc0[m][i]);
      }
    }
    __syncthreads();   // staged-A reads done before q writes? q goes to bufA: no
                       // conflict; this barrier orders bufB reads vs later P_a writes
#pragma unroll
    for (int m = 0; m < 8; ++m)
#pragma unroll
      for (int i = 0; i < 2; ++i) {
        const int col = 32 * w + 16 * i + l16;
        const float bv = ba[col];
#pragma unroll
        for (int r = 0; r < 4; ++r)
          bufA[(16 * m + quad * 4 + r) * 264 + col] = (bf16)(acc0[m][i][r] + bv);
      }
  }
  __syncthreads();   // b1: q in bufA, bits_s ready

  // ---- p1: P = sigmoid(q @ x^T), 128 rows in regs; B streamed ONCE ----
  float p[8][4] = {};
  {
    f32x4 acc1[8][4] = {};   // 128 f32/thread: rows 16m+4q+r, cols 64w+16jt+l16
#pragma unroll
    for (int ks = 0; ks < 8; ++ks) {
      bf16x8 bx[4];
#pragma unroll
      for (int jt = 0; jt < 4; ++jt)
        bx[jt] = Xbp[UIDX((4 * w + jt) * 8 + ks)];
#pragma unroll
      for (int m = 0; m < 8; ++m) {
        const bf16x8 af = *(const bf16x8*)&bufA[(16 * m + l16) * 264 + ks * 32 + quad * 8];
#pragma unroll
        for (int jt = 0; jt < 4; ++jt)
          acc1[m][jt] = MFMA16(af, bx[jt], acc1[m][jt]);
      }
    }
    __syncthreads();   // b2a: all q reads done; bufA may now be overwritten (P_b)

#pragma unroll
    for (int jt = 0; jt < 4; ++jt) {
      const int lcol = 64 * w + jt * 16 + l16;
      const int piece = 4 * w + jt;
#pragma unroll
      for (int m = 0; m < 8; ++m)
#pragma unroll
        for (int r = 0; r < 4; ++r) {
          const int row = 16 * m + quad * 4 + r;
          const int grow = row0 + row;
          float av;
          if (bits_in) {
            const unsigned short m16 = ((const unsigned short*)bits_s)[row * 32 + piece];
            av = (float)((m16 >> l16) & 1);
          } else {
            av = __builtin_nontemporal_load(
                adj + ((size_t)b * N_ + grow) * N_ + lcol);
          }
          const bool diag = (grow == lcol);
          if (bits_out) {
            const unsigned long long bal = __ballot(diag || av != 0.0f);
            if (l16 == 0)
              bits_out[((size_t)b * N_ + grow) * 32 + piece] =
                  (unsigned short)((bal >> (quad * 16)) & 0xFFFFull);
          }
          const float sg = sigmoidf_(acc1[m][jt][r]);
          const float v = diag ? (sg + 1e-5f) : sg * av;
          const bf16 bv = (bf16)v;
          if (row < 64) bufB[row * 520 + lcol] = bv;
          else          bufA[(row - 64) * 520 + lcol] = bv;
          p[m][r] += (float)v;
        }
    }
  }
#pragma unroll
  for (int m = 0; m < 8; ++m)
#pragma unroll
    for (int r = 0; r < 4; ++r) {
#pragma unroll
      for (int msk = 1; msk < 16; msk <<= 1) p[m][r] += __shfl_xor(p[m][r], msk, 64);
    }
  if (l16 == 0) {
#pragma unroll
    for (int m = 0; m < 8; ++m)
#pragma unroll
      for (int r = 0; r < 4; ++r) psum[w][16 * m + quad * 4 + r] = p[m][r];
  }
  __syncthreads();   // b2b
  if (tid < 128) {
    float s = 0.0f;
#pragma unroll
    for (int ww = 0; ww < 8; ++ww) s += psum[ww][tid];
    rinvs[tid] = 1.0f / s;
  }
  __syncthreads();   // b3

  // ---- p2: normalize both halves; attls f32 NT out; bf16 back to LDS ----
  const size_t abase = ((size_t)b * N_ + row0) * N_;
#pragma unroll
  for (int e = 0; e < 32; ++e) {
    const int idx = tid + e * 512;
    const int row = idx >> 7, c4 = (idx & 127) * 4;
    const float ri = rinvs[row];
    bf16* cell = (row < 64) ? &bufB[row * 520 + c4] : &bufA[(row - 64) * 520 + c4];
    bf16x4 pv = *(const bf16x4*)cell;
    f32x4 nv;
    nv[0] = (float)pv[0] * ri; nv[1] = (float)pv[1] * ri;
    nv[2] = (float)pv[2] * ri; nv[3] = (float)pv[3] * ri;
    __builtin_nontemporal_store(nv, (f32x4*)(outA + abase + (size_t)row * N_ + c4));
    bf16x4 o;
    o[0] = (bf16)nv[0]; o[1] = (bf16)nv[1]; o[2] = (bf16)nv[2]; o[3] = (bf16)nv[3];
    *(bf16x4*)cell = o;
  }
  __syncthreads();   // b4

  // ---- p3: x' = P @ x; xT streamed ONCE against both P halves ----
  {
    f32x4 acc3[8][2] = {};
#pragma unroll
    for (int ks = 0; ks < 16; ++ks) {
      bf16x8 bt[2];
#pragma unroll
      for (int i = 0; i < 2; ++i)
        bt[i] = Xtp[UIDX((2 * w + i) * 16 + ks)];
#pragma unroll
      for (int m = 0; m < 8; ++m) {
        const bf16x8 af = (m < 4)
            ? *(const bf16x8*)&bufB[(16 * m + l16) * 520 + ks * 32 + quad * 8]
            : *(const bf16x8*)&bufA[(16 * (m - 4) + l16) * 520 + ks * 32 + quad * 8];
#pragma unroll
        for (int i = 0; i < 2; ++i) acc3[m][i] = MFMA16(af, bt[i], acc3[m][i]);
      }
    }
    __syncthreads();   // b5a: all P reads done before x' overwrites bufA
#pragma unroll
    for (int m = 0; m < 8; ++m)
#pragma unroll
      for (int i = 0; i < 2; ++i) {
        const int d = 32 * w + 16 * i + l16;
#pragma unroll
        for (int r = 0; r < 4; ++r)
          bufA[(16 * m + quad * 4 + r) * 264 + d] = (bf16)acc3[m][i][r];
      }
  }
  __syncthreads();   // b5b: x' in bufA

  // ---- p4: h = relu(x' @ W0^T + b0) -> bufB ----
  {
    f32x4 acc[8][2] = {};
#pragma unroll
    for (int ks = 0; ks < 8; ++ks) {
      bf16x8 bw[2];
#pragma unroll
      for (int i = 0; i < 2; ++i)
        bw[i] = W08[UIDX((2 * w + i) * 8 + ks)];
#pragma unroll
      for (int m = 0; m < 8; ++m) {
        const bf16x8 af = *(const bf16x8*)&bufA[(16 * m + l16) * 264 + ks * 32 + quad * 8];
#pragma unroll
        for (int i = 0; i < 2; ++i) acc[m][i] = MFMA16(af, bw[i], acc[m][i]);
      }
    }
#pragma unroll
    for (int m = 0; m < 8; ++m)
#pragma unroll
      for (int i = 0; i < 2; ++i) {
        const int col = 32 * w + 16 * i + l16;
        const float bv = b0[col];
#pragma unroll
        for (int r = 0; r < 4; ++r)
          bufB[(16 * m + quad * 4 + r) * 264 + col] = (bf16)fmaxf(acc[m][i][r] + bv, 0.0f);
      }
  }
  __syncthreads();   // b6: h in bufB; x' (bufA) dead

  // ---- p5: x = relu(h @ W1^T + b1) + resid; emit packed outputs ----
  {
    // stage residual units -> bufA (stride 264)
#pragma unroll
    for (int j = 0; j < 8; ++j) {
      const int uu = w * 8 + j;
      const int rr = uu >> 3, kc = uu & 7;
      const bf16x8 v = Xbp[UIDX(((row0 >> 4) + rr) * 8 + kc)];
      *(bf16x8*)&bufA[(rr * 16 + l16) * 264 + kc * 32 + quad * 8] = v;
    }
    f32x4 acc[8][2] = {};
#pragma unroll
    for (int ks = 0; ks < 8; ++ks) {
      bf16x8 bw[2];
#pragma unroll
      for (int i = 0; i < 2; ++i)
        bw[i] = W18[UIDX((2 * w + i) * 8 + ks)];
#pragma unroll
      for (int m = 0; m < 8; ++m) {
        const bf16x8 af = *(const bf16x8*)&bufB[(16 * m + l16) * 264 + ks * 32 + quad * 8];
#pragma unroll
        for (int i = 0; i < 2; ++i) acc[m][i] = MFMA16(af, bw[i], acc[m][i]);
      }
    }
    __syncthreads();   // b7: resid writes visible to all

#pragma unroll
    for (int m = 0; m < 8; ++m)
#pragma unroll
      for (int i = 0; i < 2; ++i) {
        const int d = 32 * w + 16 * i + l16;
        const float bv = b1[d];
#pragma unroll
        for (int r = 0; r < 4; ++r) {
          const int nl = 16 * m + quad * 4 + r;
          const float x0 = (float)bufA[nl * 264 + d];
          const float t2 = fmaxf(acc[m][i][r] + bv, 0.0f) + x0;
          bufA[nl * 264 + d] = (bf16)t2;   // own cell after b7: no race
        }
      }
    __syncthreads();   // b8: output strip staged in bufA [128][264]

    // packed xb_out: 64 units, dense 1KB stores
#pragma unroll
    for (int j = 0; j < 8; ++j) {
      const int uu = w * 8 + j;
      const int rr = uu >> 3, kc = uu & 7;
      const bf16x8 v = *(const bf16x8*)&bufA[(rr * 16 + l16) * 264 + kc * 32 + quad * 8];
      XbpO[UIDX(((row0 >> 4) + rr) * 8 + kc)] = v;
    }
    // packed xT_out: 64 units (LDS transpose reads), dense 1KB stores
#pragma unroll
    for (int j = 0; j < 8; ++j) {
      const int uu = w * 8 + j;
      const int d16 = uu >> 2, nk = uu & 3;
      const int d = d16 * 16 + l16;
      bf16x8 v;
#pragma unroll
      for (int e = 0; e < 8; ++e)
        v[e] = bufA[(nk * 32 + quad * 8 + e) * 264 + d];
      XtpO[UIDX(d16 * 16 + (row0 >> 5) + nk)] = v;
    }
  }
}

// ---------------------------------------------------------------------------
// final_proj: out = x @ Wf^T + bf (f32). A from packed xb (dense), no LDS.
// ---------------------------------------------------------------------------
__global__ __launch_bounds__(256, 4) void final_proj(
    const bf16* __restrict__ xbpk, const bf16* __restrict__ Wfp,
    const float* __restrict__ bfv, float* __restrict__ outX)
{
  const int tid = threadIdx.x, w = tid >> 6, lane = tid & 63;
  const int l16 = lane & 15, quad = lane >> 4;
  const int wg = blockIdx.x;
  const int lid = (wg & 7) * 128 + (wg >> 3);
  const int row0g = lid * 32;
  const int b = row0g >> 9, n0 = row0g & 511;
  const bf16x8* Xbp = (const bf16x8*)xbpk + (size_t)b * 16384;
  const bf16x8* Wf8 = (const bf16x8*)Wfp;
  f32x4 acc[2][4] = {};
#pragma unroll
  for (int ks = 0; ks < 8; ++ks) {
    bf16x8 af[2];
#pragma unroll
    for (int m = 0; m < 2; ++m)
      af[m] = Xbp[UIDX(((n0 >> 4) + m) * 8 + ks)];
    bf16x8 bw[4];
#pragma unroll
    for (int i = 0; i < 4; ++i)
      bw[i] = Wf8[UIDX((4 * w + i) * 8 + ks)];
#pragma unroll
    for (int m = 0; m < 2; ++m)
#pragma unroll
      for (int i = 0; i < 4; ++i) acc[m][i] = MFMA16(af[m], bw[i], acc[m][i]);
  }
#pragma unroll
  for (int m = 0; m < 2; ++m)
#pragma unroll
    for (int i = 0; i < 4; ++i) {
      const int col = 64 * w + 16 * i + l16;
      const float bv = bfv[col];
#pragma unroll
      for (int r = 0; r < 4; ++r) {
        const size_t R = (size_t)row0g + 16 * m + quad * 4 + r;
        __builtin_nontemporal_store(acc[m][i][r] + bv, outX + R * D_ + col);
      }
    }
}

extern "C" void kernel_launch(void* const* d_in, const int* in_sizes, int n_in,
                              void* d_out, int out_size, void* d_ws, size_t ws_size,
                              hipStream_t stream)
{
  const float* x_in  = (const float*)d_in[0];
  const float* adj   = (const float*)d_in[1];
  const float* wattn = (const float*)d_in[2];
  const float* battn = (const float*)d_in[3];
  const float* w0    = (const float*)d_in[4];
  const float* b0    = (const float*)d_in[5];
  const float* w1    = (const float*)d_in[6];
  const float* b1    = (const float*)d_in[7];
  const float* wf    = (const float*)d_in[8];
  const float* bfin  = (const float*)d_in[9];

  float* out_x    = (float*)d_out;                     // [B,N,D] f32
  float* out_attn = out_x + (size_t)B_ * N_ * D_;      // [L,B,N,N]

  const size_t XBN = (size_t)B_ * N_ * D_;
  const int DD2 = D_ * D_;
  bf16* wb   = (bf16*)d_ws;                            // 13*D*D packed weights
  bf16* xbp0 = wb + 13 * DD2;
  bf16* xtp0 = xbp0 + XBN;
  bf16* xbp1 = xtp0 + XBN;
  bf16* xtp1 = xbp1 + XBN;
  unsigned short* bits = (unsigned short*)(xtp1 + XBN);// [B,N,32] uint16

  // pack weights (f32 -> packed bf16 fragments)
  pack_w<<<dim3(4 * 32), 256, 0, stream>>>(wattn, wb);
  pack_w<<<dim3(4 * 32), 256, 0, stream>>>(w0, wb + 4 * DD2);
  pack_w<<<dim3(4 * 32), 256, 0, stream>>>(w1, wb + 8 * DD2);
  pack_w<<<dim3(1 * 32), 256, 0, stream>>>(wf, wb + 12 * DD2);

  // x -> packed xb + packed xT
  init_pack<<<dim3(8192), 256, 0, stream>>>(x_in, xbp0, xtp0);

  bf16* xbps[2] = {xbp0, xbp1};
  bf16* xtps[2] = {xtp0, xtp1};
  for (int l = 0; l < L_; ++l) {
    const int pi = l & 1, po = 1 - pi;
    gat_layer<<<dim3((N_ / 128) * B_), 512, 0, stream>>>(
        xbps[pi], xtps[pi], xbps[po], xtps[po],
        wb + l * DD2, battn + l * D_,
        wb + (4 + l) * DD2, b0 + l * D_,
        wb + (8 + l) * DD2, b1 + l * D_,
        adj, (l == 0) ? nullptr : bits, (l == 0) ? bits : nullptr,
        out_attn + (size_t)l * B_ * N_ * N_);
  }
  final_proj<<<dim3((B_ * N_) / 32), 256, 0, stream>>>(
      xbps[0], wb + 12 * DD2, bfin, out_x);
}

// Round 10
// 712.556 us; speedup vs baseline: 1.0293x; 1.0293x over previous
//
#include <hip/hip_runtime.h>
#include <cstdint>

#define B_ 64
#define N_ 512
#define D_ 256
#define L_ 4

typedef __bf16 bf16;
typedef __attribute__((ext_vector_type(8))) __bf16 bf16x8;
typedef __attribute__((ext_vector_type(4))) __bf16 bf16x4;
typedef __attribute__((ext_vector_type(4))) float f32x4;

#define MFMA16(a, b, c) __builtin_amdgcn_mfma_f32_16x16x32_bf16((a), (b), (c), 0, 0, 0)

__device__ __forceinline__ float sigmoidf_(float z) {
  return 1.0f / (1.0f + __expf(-z));
}

// ===========================================================================
// R10 = R8 base (64-row strips, 512 thr, best @725us) + de-drained barriers.
// Diagnosis: hipcc emits s_waitcnt vmcnt(0) lgkmcnt(0) before every
// s_barrier -> each of the 8 phases drains ALL in-flight global ops (incl.
// the 64MB attls store burst) and restarts cold with only 2 waves/SIMD to
// hide first-load latency. No thread reads another thread's GLOBAL write
// inside this kernel (all cross-thread traffic is LDS), so every barrier is
// legally lgkmcnt-only: global loads/stores stay in flight across barriers.
// Plus T14 issue-early: W0 loads issue during p3's epilogue, W1+resid loads
// during p4's epilogue - consumed after the next barrier.
// ===========================================================================

// lgkmcnt-only barrier: LDS ordering w/o vmcnt drain. sched_barrier pins
// (rule #18: MFMA can be hoisted past inline-asm waits otherwise).
#define BARSYNC() do { \
    asm volatile("s_waitcnt lgkmcnt(0)\n\ts_barrier" ::: "memory"); \
    __builtin_amdgcn_sched_barrier(0); \
  } while (0)

#define UIDX(u) (((size_t)(u)) * 64 + lane)

__global__ __launch_bounds__(256) void pack_w(
    const float* __restrict__ src, bf16* __restrict__ dst)
{
  const int tid = threadIdx.x, lane = tid & 63;
  const int U = blockIdx.x * 4 + (tid >> 6);
  const int m = U >> 7, u = U & 127;
  const int r16 = u >> 3, kc = u & 7;
  const int row = r16 * 16 + (lane & 15);
  const int k0 = kc * 32 + (lane >> 4) * 8;
  const float* s = src + (size_t)m * D_ * D_ + (size_t)row * D_ + k0;
  const float4 v0 = *(const float4*)s;
  const float4 v1 = *(const float4*)(s + 4);
  bf16x8 o;
  o[0] = (bf16)v0.x; o[1] = (bf16)v0.y; o[2] = (bf16)v0.z; o[3] = (bf16)v0.w;
  o[4] = (bf16)v1.x; o[5] = (bf16)v1.y; o[6] = (bf16)v1.z; o[7] = (bf16)v1.w;
  ((bf16x8*)dst)[(size_t)U * 64 + lane] = o;
}

__global__ __launch_bounds__(256) void init_pack(
    const float* __restrict__ x, bf16* __restrict__ xbpk, bf16* __restrict__ xTpk)
{
  const int tid = threadIdx.x, lane = tid & 63;
  const int U = blockIdx.x * 4 + (tid >> 6);    // 0..32767
  const int b = U >> 9, u = U & 511;
  if (u < 256) {            // xbpk unit: r16 = n/16, kc = d/32
    const int n = (u >> 3) * 16 + (lane & 15);
    const int d = (u & 7) * 32 + (lane >> 4) * 8;
    const float* s = x + ((size_t)(b * N_ + n)) * D_ + d;
    const float4 v0 = *(const float4*)s;
    const float4 v1 = *(const float4*)(s + 4);
    bf16x8 o;
    o[0] = (bf16)v0.x; o[1] = (bf16)v0.y; o[2] = (bf16)v0.z; o[3] = (bf16)v0.w;
    o[4] = (bf16)v1.x; o[5] = (bf16)v1.y; o[6] = (bf16)v1.z; o[7] = (bf16)v1.w;
    ((bf16x8*)xbpk)[((size_t)b * 256 + u) * 64 + lane] = o;
  } else {                  // xTpk unit: r16 = d/16, kc = n/32
    const int u2 = u - 256;
    const int d = (u2 >> 4) * 16 + (lane & 15);
    const int n = (u2 & 15) * 32 + (lane >> 4) * 8;
    bf16x8 o;
#pragma unroll
    for (int e = 0; e < 8; ++e)
      o[e] = (bf16)x[((size_t)(b * N_ + n + e)) * D_ + d];
    ((bf16x8*)xTpk)[((size_t)b * 256 + u2) * 64 + lane] = o;
  }
}

// ---------------------------------------------------------------------------
// gat_layer: one block per (64-row strip, batch); 512 threads (8 waves);
// LDS ~104 KB -> 1 block/CU. Grid 512. lgkmcnt-only barriers throughout.
// ---------------------------------------------------------------------------
__global__ __launch_bounds__(512, 1) void gat_layer(
    const bf16* __restrict__ xbpk_in, const bf16* __restrict__ xTpk_in,
    bf16* __restrict__ xbpk_out, bf16* __restrict__ xTpk_out,
    const bf16* __restrict__ Wap, const float* __restrict__ ba,
    const bf16* __restrict__ W0p, const float* __restrict__ b0,
    const bf16* __restrict__ W1p, const float* __restrict__ b1,
    const float* __restrict__ adj, const unsigned short* __restrict__ bits_in,
    unsigned short* __restrict__ bits_out, float* __restrict__ outA)
{
  __shared__ bf16 qs[64 * 264];     // q / x' / out-stage (stride 264)  33.8KB
  __shared__ bf16 xps[64 * 520];    // P (stride 520) / h (stride 264)  66.6KB
  __shared__ float psum[8][64];     //                                   2KB
  __shared__ float rinvs[64];
  __shared__ unsigned int bits_s[1024];  // 64 rows x 32 uint16          4KB

  const int tid = threadIdx.x, w = tid >> 6, lane = tid & 63;
  const int l16 = lane & 15, quad = lane >> 4;
  const int wg = blockIdx.x;
  const int lid = (wg & 7) * 64 + (wg >> 3);   // bijective XCD swizzle
  const int b = lid >> 3;                      // 8 strips per batch
  const int row0 = (lid & 7) * 64;

  const bf16x8* Xbp = (const bf16x8*)xbpk_in + (size_t)b * 16384;
  const bf16x8* Xtp = (const bf16x8*)xTpk_in + (size_t)b * 16384;
  bf16x8* XbpO = (bf16x8*)xbpk_out + (size_t)b * 16384;
  bf16x8* XtpO = (bf16x8*)xTpk_out + (size_t)b * 16384;
  const bf16x8* Wa8 = (const bf16x8*)Wap;
  const bf16x8* W08 = (const bf16x8*)W0p;
  const bf16x8* W18 = (const bf16x8*)W1p;

  if (bits_in) {
#pragma unroll
    for (int e = 0; e < 2; ++e) {
      const int t = tid + e * 512;
      bits_s[t] = ((const unsigned int*)bits_in)[((size_t)b * N_ + row0) * 16 + t];
    }
  }

  // ---- p0: q = x @ Wa^T + ba ; A straight from packed global (dense) ----
  {
    f32x4 acc0[4][2] = {};
#pragma unroll
    for (int ks = 0; ks < 8; ++ks) {
      bf16x8 af[4];
#pragma unroll
      for (int m = 0; m < 4; ++m)
        af[m] = Xbp[UIDX(((row0 >> 4) + m) * 8 + ks)];
      bf16x8 bw[2];
#pragma unroll
      for (int i = 0; i < 2; ++i)
        bw[i] = Wa8[UIDX((2 * w + i) * 8 + ks)];
#pragma unroll
      for (int m = 0; m < 4; ++m)
#pragma unroll
        for (int i = 0; i < 2; ++i) acc0[m][i] = MFMA16(af[m], bw[i], acc0[m][i]);
    }
#pragma unroll
    for (int m = 0; m < 4; ++m)
#pragma unroll
      for (int i = 0; i < 2; ++i) {
        const int col = 32 * w + 16 * i + l16;
        const float bv = ba[col];
#pragma unroll
        for (int r = 0; r < 4; ++r)
          qs[(16 * m + quad * 4 + r) * 264 + col] = (bf16)(acc0[m][i][r] + bv);
      }
  }
  BARSYNC();   // b1: qs(q) + bits_s ready (LDS only)

  // ---- p1: P = sigmoid(q @ x^T) masked -> xps ----
  float p[4][4] = {};
  {
    f32x4 acc1[4][4] = {};
#pragma unroll
    for (int ks = 0; ks < 8; ++ks) {
      bf16x8 af[4];
#pragma unroll
      for (int m = 0; m < 4; ++m)
        af[m] = *(const bf16x8*)&qs[(16 * m + l16) * 264 + ks * 32 + quad * 8];
      bf16x8 bx[4];
#pragma unroll
      for (int jt = 0; jt < 4; ++jt)
        bx[jt] = Xbp[UIDX((4 * w + jt) * 8 + ks)];
#pragma unroll
      for (int m = 0; m < 4; ++m)
#pragma unroll
        for (int jt = 0; jt < 4; ++jt)
          acc1[m][jt] = MFMA16(af[m], bx[jt], acc1[m][jt]);
    }
#pragma unroll
    for (int jt = 0; jt < 4; ++jt) {
      const int lcol = 64 * w + jt * 16 + l16;
      const int piece = 4 * w + jt;
#pragma unroll
      for (int m = 0; m < 4; ++m)
#pragma unroll
        for (int r = 0; r < 4; ++r) {
          const int row = 16 * m + quad * 4 + r;
          const int grow = row0 + row;
          float av;
          if (bits_in) {
            const unsigned short m16 = ((const unsigned short*)bits_s)[row * 32 + piece];
            av = (float)((m16 >> l16) & 1);
          } else {
            av = __builtin_nontemporal_load(
                adj + ((size_t)b * N_ + grow) * N_ + lcol);
          }
          const bool diag = (grow == lcol);
          if (bits_out) {
            const unsigned long long bal = __ballot(diag || av != 0.0f);
            if (l16 == 0)
              bits_out[((size_t)b * N_ + row0 + 16 * m + 4 * quad + r) * 32 + piece] =
                  (unsigned short)((bal >> (quad * 16)) & 0xFFFFull);
          }
          const float sg = sigmoidf_(acc1[m][jt][r]);
          const float v = diag ? (sg + 1e-5f) : sg * av;
          const bf16 bv = (bf16)v;
          xps[row * 520 + lcol] = bv;
          p[m][r] += (float)bv;
        }
    }
  }
#pragma unroll
  for (int m = 0; m < 4; ++m)
#pragma unroll
    for (int r = 0; r < 4; ++r) {
#pragma unroll
      for (int msk = 1; msk < 16; msk <<= 1) p[m][r] += __shfl_xor(p[m][r], msk, 64);
    }
  if (l16 == 0) {
#pragma unroll
    for (int m = 0; m < 4; ++m)
#pragma unroll
      for (int r = 0; r < 4; ++r) psum[w][16 * m + quad * 4 + r] = p[m][r];
  }
  BARSYNC();   // b2
  if (tid < 64) {
    float s = 0.0f;
#pragma unroll
    for (int ww = 0; ww < 8; ++ww) s += psum[ww][tid];
    rinvs[tid] = 1.0f / s;
  }
  BARSYNC();   // b3

  // ---- p2: normalize; attls f32 NT out (stays in flight); bf16 to xps ----
  const size_t abase = ((size_t)b * N_ + row0) * N_;
#pragma unroll
  for (int e = 0; e < 16; ++e) {
    const int idx = tid + e * 512;
    const int row = idx >> 7, c4 = (idx & 127) * 4;
    const float ri = rinvs[row];
    bf16x4 pv = *(const bf16x4*)&xps[row * 520 + c4];
    f32x4 nv;
    nv[0] = (float)pv[0] * ri; nv[1] = (float)pv[1] * ri;
    nv[2] = (float)pv[2] * ri; nv[3] = (float)pv[3] * ri;
    __builtin_nontemporal_store(nv, (f32x4*)(outA + abase + (size_t)row * N_ + c4));
    bf16x4 o;
    o[0] = (bf16)nv[0]; o[1] = (bf16)nv[1]; o[2] = (bf16)nv[2]; o[3] = (bf16)nv[3];
    *(bf16x4*)&xps[row * 520 + c4] = o;
  }
  BARSYNC();   // b4: attls stores NOT drained here (lgkm only)

  // ---- p3: x' = P @ x (B = xTpk dense), K = 512 -> qs ----
  {
    f32x4 acc3[4][2] = {};
#pragma unroll
    for (int ks = 0; ks < 16; ++ks) {
      bf16x8 af[4];
#pragma unroll
      for (int m = 0; m < 4; ++m)
        af[m] = *(const bf16x8*)&xps[(16 * m + l16) * 520 + ks * 32 + quad * 8];
      bf16x8 bt[2];
#pragma unroll
      for (int i = 0; i < 2; ++i)
        bt[i] = Xtp[UIDX((2 * w + i) * 16 + ks)];
#pragma unroll
      for (int m = 0; m < 4; ++m)
#pragma unroll
        for (int i = 0; i < 2; ++i) acc3[m][i] = MFMA16(af[m], bt[i], acc3[m][i]);
    }
    // T14 issue-early: W0 fragment loads fly across b5, consumed in p4
    bf16x8 w0r[16];
#pragma unroll
    for (int j = 0; j < 16; ++j)
      w0r[j] = W08[UIDX((2 * w + (j >> 3)) * 8 + (j & 7))];
    __builtin_amdgcn_sched_barrier(0);
#pragma unroll
    for (int m = 0; m < 4; ++m)
#pragma unroll
      for (int i = 0; i < 2; ++i) {
        const int d = 32 * w + 16 * i + l16;
#pragma unroll
        for (int r = 0; r < 4; ++r)
          qs[(16 * m + quad * 4 + r) * 264 + d] = (bf16)acc3[m][i][r];
      }
    BARSYNC();   // b5: x' in qs

    // ---- p4: h = relu(x' @ W0^T + b0) -> xps (stride 264) ----
    f32x4 acc[4][2] = {};
#pragma unroll
    for (int ks = 0; ks < 8; ++ks) {
      bf16x8 af[4];
#pragma unroll
      for (int m = 0; m < 4; ++m)
        af[m] = *(const bf16x8*)&qs[(16 * m + l16) * 264 + ks * 32 + quad * 8];
#pragma unroll
      for (int m = 0; m < 4; ++m)
#pragma unroll
        for (int i = 0; i < 2; ++i)
          acc[m][i] = MFMA16(af[m], w0r[i * 8 + ks], acc[m][i]);
    }
    // T14 issue-early: W1 + residual loads fly across b6, consumed in p5
    bf16x8 w1r[16];
#pragma unroll
    for (int j = 0; j < 16; ++j)
      w1r[j] = W18[UIDX((2 * w + (j >> 3)) * 8 + (j & 7))];
    bf16x8 resid[4];
#pragma unroll
    for (int j = 0; j < 4; ++j) {
      const int uu = w * 4 + j;
      resid[j] = Xbp[UIDX(((row0 >> 4) + (uu >> 3)) * 8 + (uu & 7))];
    }
    __builtin_amdgcn_sched_barrier(0);
#pragma unroll
    for (int m = 0; m < 4; ++m)
#pragma unroll
      for (int i = 0; i < 2; ++i) {
        const int col = 32 * w + 16 * i + l16;
        const float bv = b0[col];
#pragma unroll
        for (int r = 0; r < 4; ++r)
          xps[(16 * m + quad * 4 + r) * 264 + col] = (bf16)fmaxf(acc[m][i][r] + bv, 0.0f);
      }
    BARSYNC();   // b6: h in xps; qs (x') dead

    // ---- p5: x = relu(h @ W1^T + b1) + resid; emit packed outputs ----
    // stage residual strip (regs -> LDS, loads already in flight)
#pragma unroll
    for (int j = 0; j < 4; ++j) {
      const int uu = w * 4 + j;
      const int rr = uu >> 3, kc = uu & 7;
      *(bf16x8*)&qs[(rr * 16 + l16) * 264 + kc * 32 + quad * 8] = resid[j];
    }
    f32x4 acc5[4][2] = {};
#pragma unroll
    for (int ks = 0; ks < 8; ++ks) {
      bf16x8 af[4];
#pragma unroll
      for (int m = 0; m < 4; ++m)
        af[m] = *(const bf16x8*)&xps[(16 * m + l16) * 264 + ks * 32 + quad * 8];
#pragma unroll
      for (int m = 0; m < 4; ++m)
#pragma unroll
        for (int i = 0; i < 2; ++i)
          acc5[m][i] = MFMA16(af[m], w1r[i * 8 + ks], acc5[m][i]);
    }
    BARSYNC();   // b7: resid writes visible to all

#pragma unroll
    for (int m = 0; m < 4; ++m)
#pragma unroll
      for (int i = 0; i < 2; ++i) {
        const int d = 32 * w + 16 * i + l16;
        const float bv = b1[d];
#pragma unroll
        for (int r = 0; r < 4; ++r) {
          const int nl = 16 * m + quad * 4 + r;
          const float x0 = (float)qs[nl * 264 + d];
          const float t2 = fmaxf(acc5[m][i][r] + bv, 0.0f) + x0;
          qs[nl * 264 + d] = (bf16)t2;   // own cell after b7: no race
        }
      }
    BARSYNC();   // b8: output strip staged in qs [64][264]

    // packed xb_out: 32 units, dense 1KB stores
#pragma unroll
    for (int j = 0; j < 4; ++j) {
      const int uu = w * 4 + j;
      const int rr = uu >> 3, kc = uu & 7;
      const bf16x8 v = *(const bf16x8*)&qs[(rr * 16 + l16) * 264 + kc * 32 + quad * 8];
      XbpO[UIDX(((row0 >> 4) + rr) * 8 + kc)] = v;
    }
    // packed xT_out: 32 units (LDS transpose reads), dense 1KB stores
#pragma unroll
    for (int j = 0; j < 4; ++j) {
      const int uu = w * 4 + j;
      const int d16 = uu >> 1, nk = uu & 1;
      const int d = d16 * 16 + l16;
      bf16x8 v;
#pragma unroll
      for (int e = 0; e < 8; ++e)
        v[e] = qs[(nk * 32 + quad * 8 + e) * 264 + d];
      XtpO[UIDX(d16 * 16 + (row0 >> 5) + nk)] = v;
    }
  }
}

// ---------------------------------------------------------------------------
// final_proj: out = x @ Wf^T + bf (f32). A from packed xb (dense), no LDS.
// ---------------------------------------------------------------------------
__global__ __launch_bounds__(256, 4) void final_proj(
    const bf16* __restrict__ xbpk, const bf16* __restrict__ Wfp,
    const float* __restrict__ bfv, float* __restrict__ outX)
{
  const int tid = threadIdx.x, w = tid >> 6, lane = tid & 63;
  const int l16 = lane & 15, quad = lane >> 4;
  const int wg = blockIdx.x;
  const int lid = (wg & 7) * 128 + (wg >> 3);
  const int row0g = lid * 32;
  const int b = row0g >> 9, n0 = row0g & 511;
  const bf16x8* Xbp = (const bf16x8*)xbpk + (size_t)b * 16384;
  const bf16x8* Wf8 = (const bf16x8*)Wfp;
  f32x4 acc[2][4] = {};
#pragma unroll
  for (int ks = 0; ks < 8; ++ks) {
    bf16x8 af[2];
#pragma unroll
    for (int m = 0; m < 2; ++m)
      af[m] = Xbp[UIDX(((n0 >> 4) + m) * 8 + ks)];
    bf16x8 bw[4];
#pragma unroll
    for (int i = 0; i < 4; ++i)
      bw[i] = Wf8[UIDX((4 * w + i) * 8 + ks)];
#pragma unroll
    for (int m = 0; m < 2; ++m)
#pragma unroll
      for (int i = 0; i < 4; ++i) acc[m][i] = MFMA16(af[m], bw[i], acc[m][i]);
  }
#pragma unroll
  for (int m = 0; m < 2; ++m)
#pragma unroll
    for (int i = 0; i < 4; ++i) {
      const int col = 64 * w + 16 * i + l16;
      const float bv = bfv[col];
#pragma unroll
      for (int r = 0; r < 4; ++r) {
        const size_t R = (size_t)row0g + 16 * m + quad * 4 + r;
        __builtin_nontemporal_store(acc[m][i][r] + bv, outX + R * D_ + col);
      }
    }
}

extern "C" void kernel_launch(void* const* d_in, const int* in_sizes, int n_in,
                              void* d_out, int out_size, void* d_ws, size_t ws_size,
                              hipStream_t stream)
{
  const float* x_in  = (const float*)d_in[0];
  const float* adj   = (const float*)d_in[1];
  const float* wattn = (const float*)d_in[2];
  const float* battn = (const float*)d_in[3];
  const float* w0    = (const float*)d_in[4];
  const float* b0    = (const float*)d_in[5];
  const float* w1    = (const float*)d_in[6];
  const float* b1    = (const float*)d_in[7];
  const float* wf    = (const float*)d_in[8];
  const float* bfin  = (const float*)d_in[9];

  float* out_x    = (float*)d_out;                     // [B,N,D] f32
  float* out_attn = out_x + (size_t)B_ * N_ * D_;      // [L,B,N,N]

  const size_t XBN = (size_t)B_ * N_ * D_;
  const int DD2 = D_ * D_;
  bf16* wb   = (bf16*)d_ws;                            // 13*D*D packed weights
  bf16* xbp0 = wb + 13 * DD2;
  bf16* xtp0 = xbp0 + XBN;
  bf16* xbp1 = xtp0 + XBN;
  bf16* xtp1 = xbp1 + XBN;
  unsigned short* bits = (unsigned short*)(xtp1 + XBN);// [B,N,32] uint16

  // pack weights (f32 -> packed bf16 fragments)
  pack_w<<<dim3(4 * 32), 256, 0, stream>>>(wattn, wb);
  pack_w<<<dim3(4 * 32), 256, 0, stream>>>(w0, wb + 4 * DD2);
  pack_w<<<dim3(4 * 32), 256, 0, stream>>>(w1, wb + 8 * DD2);
  pack_w<<<dim3(1 * 32), 256, 0, stream>>>(wf, wb + 12 * DD2);

  // x -> packed xb + packed xT
  init_pack<<<dim3(8192), 256, 0, stream>>>(x_in, xbp0, xtp0);

  bf16* xbps[2] = {xbp0, xbp1};
  bf16* xtps[2] = {xtp0, xtp1};
  for (int l = 0; l < L_; ++l) {
    const int pi = l & 1, po = 1 - pi;
    gat_layer<<<dim3((N_ / 64) * B_), 512, 0, stream>>>(
        xbps[pi], xtps[pi], xbps[po], xtps[po],
        wb + l * DD2, battn + l * D_,
        wb + (4 + l) * DD2, b0 + l * D_,
        wb + (8 + l) * DD2, b1 + l * D_,
        adj, (l == 0) ? nullptr : bits, (l == 0) ? bits : nullptr,
        out_attn + (size_t)l * B_ * N_ * N_);
  }
  final_proj<<<dim3((B_ * N_) / 32), 256, 0, stream>>>(
      xbps[0], wb + 12 * DD2, bfin, out_x);
}

// Round 11
// 697.269 us; speedup vs baseline: 1.0519x; 1.0219x over previous
//
#include <hip/hip_runtime.h>
#include <cstdint>

#define B_ 64
#define N_ 512
#define D_ 256
#define L_ 4

typedef __bf16 bf16;
typedef __attribute__((ext_vector_type(8))) __bf16 bf16x8;
typedef __attribute__((ext_vector_type(4))) __bf16 bf16x4;
typedef __attribute__((ext_vector_type(4))) float f32x4;

#define MFMA16(a, b, c) __builtin_amdgcn_mfma_f32_16x16x32_bf16((a), (b), (c), 0, 0, 0)

__device__ __forceinline__ float sigmoidf_(float z) {
  return 1.0f / (1.0f + __expf(-z));
}

// ===========================================================================
// R11 = R10 (64-row strips, lgkm-only barriers, packed I/O) + DEEP cross-
// barrier prefetch of the two dominant B-streams (the R10 mechanism scaled
// up): p1's first-half Xbp stream issues during p0's epilogue (crosses b1 in
// flight); p3's first-half Xtp stream issues after p1's epilogue (crosses
// b2/b3/p2, covered by reduce+normalize+attls burst). Legal only because
// barriers are lgkmcnt-only (R10); with vmcnt(0) drains this was forced
// cold (R3's null). W0/W1/resid prefetches kept from R10.
// ===========================================================================

// lgkmcnt-only barrier: LDS ordering w/o vmcnt drain. sched_barrier pins
// (rule #18: MFMA can be hoisted past inline-asm waits otherwise).
#define BARSYNC() do { \
    asm volatile("s_waitcnt lgkmcnt(0)\n\ts_barrier" ::: "memory"); \
    __builtin_amdgcn_sched_barrier(0); \
  } while (0)

#define UIDX(u) (((size_t)(u)) * 64 + lane)

__global__ __launch_bounds__(256) void pack_w(
    const float* __restrict__ src, bf16* __restrict__ dst)
{
  const int tid = threadIdx.x, lane = tid & 63;
  const int U = blockIdx.x * 4 + (tid >> 6);
  const int m = U >> 7, u = U & 127;
  const int r16 = u >> 3, kc = u & 7;
  const int row = r16 * 16 + (lane & 15);
  const int k0 = kc * 32 + (lane >> 4) * 8;
  const float* s = src + (size_t)m * D_ * D_ + (size_t)row * D_ + k0;
  const float4 v0 = *(const float4*)s;
  const float4 v1 = *(const float4*)(s + 4);
  bf16x8 o;
  o[0] = (bf16)v0.x; o[1] = (bf16)v0.y; o[2] = (bf16)v0.z; o[3] = (bf16)v0.w;
  o[4] = (bf16)v1.x; o[5] = (bf16)v1.y; o[6] = (bf16)v1.z; o[7] = (bf16)v1.w;
  ((bf16x8*)dst)[(size_t)U * 64 + lane] = o;
}

__global__ __launch_bounds__(256) void init_pack(
    const float* __restrict__ x, bf16* __restrict__ xbpk, bf16* __restrict__ xTpk)
{
  const int tid = threadIdx.x, lane = tid & 63;
  const int U = blockIdx.x * 4 + (tid >> 6);    // 0..32767
  const int b = U >> 9, u = U & 511;
  if (u < 256) {            // xbpk unit: r16 = n/16, kc = d/32
    const int n = (u >> 3) * 16 + (lane & 15);
    const int d = (u & 7) * 32 + (lane >> 4) * 8;
    const float* s = x + ((size_t)(b * N_ + n)) * D_ + d;
    const float4 v0 = *(const float4*)s;
    const float4 v1 = *(const float4*)(s + 4);
    bf16x8 o;
    o[0] = (bf16)v0.x; o[1] = (bf16)v0.y; o[2] = (bf16)v0.z; o[3] = (bf16)v0.w;
    o[4] = (bf16)v1.x; o[5] = (bf16)v1.y; o[6] = (bf16)v1.z; o[7] = (bf16)v1.w;
    ((bf16x8*)xbpk)[((size_t)b * 256 + u) * 64 + lane] = o;
  } else {                  // xTpk unit: r16 = d/16, kc = n/32
    const int u2 = u - 256;
    const int d = (u2 >> 4) * 16 + (lane & 15);
    const int n = (u2 & 15) * 32 + (lane >> 4) * 8;
    bf16x8 o;
#pragma unroll
    for (int e = 0; e < 8; ++e)
      o[e] = (bf16)x[((size_t)(b * N_ + n + e)) * D_ + d];
    ((bf16x8*)xTpk)[((size_t)b * 256 + u2) * 64 + lane] = o;
  }
}

// ---------------------------------------------------------------------------
// gat_layer: one block per (64-row strip, batch); 512 threads (8 waves);
// LDS ~104 KB -> 1 block/CU. Grid 512. lgkm-only barriers + deep prefetch.
// ---------------------------------------------------------------------------
__global__ __launch_bounds__(512, 1) void gat_layer(
    const bf16* __restrict__ xbpk_in, const bf16* __restrict__ xTpk_in,
    bf16* __restrict__ xbpk_out, bf16* __restrict__ xTpk_out,
    const bf16* __restrict__ Wap, const float* __restrict__ ba,
    const bf16* __restrict__ W0p, const float* __restrict__ b0,
    const bf16* __restrict__ W1p, const float* __restrict__ b1,
    const float* __restrict__ adj, const unsigned short* __restrict__ bits_in,
    unsigned short* __restrict__ bits_out, float* __restrict__ outA)
{
  __shared__ bf16 qs[64 * 264];     // q / x' / out-stage (stride 264)  33.8KB
  __shared__ bf16 xps[64 * 520];    // P (stride 520) / h (stride 264)  66.6KB
  __shared__ float psum[8][64];     //                                   2KB
  __shared__ float rinvs[64];
  __shared__ unsigned int bits_s[1024];  // 64 rows x 32 uint16          4KB

  const int tid = threadIdx.x, w = tid >> 6, lane = tid & 63;
  const int l16 = lane & 15, quad = lane >> 4;
  const int wg = blockIdx.x;
  const int lid = (wg & 7) * 64 + (wg >> 3);   // bijective XCD swizzle
  const int b = lid >> 3;                      // 8 strips per batch
  const int row0 = (lid & 7) * 64;

  const bf16x8* Xbp = (const bf16x8*)xbpk_in + (size_t)b * 16384;
  const bf16x8* Xtp = (const bf16x8*)xTpk_in + (size_t)b * 16384;
  bf16x8* XbpO = (bf16x8*)xbpk_out + (size_t)b * 16384;
  bf16x8* XtpO = (bf16x8*)xTpk_out + (size_t)b * 16384;
  const bf16x8* Wa8 = (const bf16x8*)Wap;
  const bf16x8* W08 = (const bf16x8*)W0p;
  const bf16x8* W18 = (const bf16x8*)W1p;

  if (bits_in) {
#pragma unroll
    for (int e = 0; e < 2; ++e) {
      const int t = tid + e * 512;
      bits_s[t] = ((const unsigned int*)bits_in)[((size_t)b * N_ + row0) * 16 + t];
    }
  }

  // ---- p0: q = x @ Wa^T + ba ; A straight from packed global (dense) ----
  {
    f32x4 acc0[4][2] = {};
#pragma unroll
    for (int ks = 0; ks < 8; ++ks) {
      bf16x8 af[4];
#pragma unroll
      for (int m = 0; m < 4; ++m)
        af[m] = Xbp[UIDX(((row0 >> 4) + m) * 8 + ks)];
      bf16x8 bw[2];
#pragma unroll
      for (int i = 0; i < 2; ++i)
        bw[i] = Wa8[UIDX((2 * w + i) * 8 + ks)];
#pragma unroll
      for (int m = 0; m < 4; ++m)
#pragma unroll
        for (int i = 0; i < 2; ++i) acc0[m][i] = MFMA16(af[m], bw[i], acc0[m][i]);
    }
#pragma unroll
    for (int m = 0; m < 4; ++m)
#pragma unroll
      for (int i = 0; i < 2; ++i) {
        const int col = 32 * w + 16 * i + l16;
        const float bv = ba[col];
#pragma unroll
        for (int r = 0; r < 4; ++r)
          qs[(16 * m + quad * 4 + r) * 264 + col] = (bf16)(acc0[m][i][r] + bv);
      }
  }
  // T14-deep: p1's first-half B-stream (ks 0..3) issues here, crosses b1
  bf16x8 bxp[4][4];
#pragma unroll
  for (int ks = 0; ks < 4; ++ks)
#pragma unroll
    for (int jt = 0; jt < 4; ++jt)
      bxp[ks][jt] = Xbp[UIDX((4 * w + jt) * 8 + ks)];
  __builtin_amdgcn_sched_barrier(0);
  BARSYNC();   // b1: qs(q) + bits_s ready (LDS only; bxp stays in flight)

  // ---- p1: P = sigmoid(q @ x^T) masked -> xps ----
  float p[4][4] = {};
  bf16x8 btp[8][2];   // p3 first-half prefetch (filled after p1 MFMA)
  {
    f32x4 acc1[4][4] = {};
#pragma unroll
    for (int ks = 0; ks < 8; ++ks) {
      bf16x8 af[4];
#pragma unroll
      for (int m = 0; m < 4; ++m)
        af[m] = *(const bf16x8*)&qs[(16 * m + l16) * 264 + ks * 32 + quad * 8];
      bf16x8 bx[4];
#pragma unroll
      for (int jt = 0; jt < 4; ++jt)
        bx[jt] = (ks < 4) ? bxp[ks][jt] : Xbp[UIDX((4 * w + jt) * 8 + ks)];
#pragma unroll
      for (int m = 0; m < 4; ++m)
#pragma unroll
        for (int jt = 0; jt < 4; ++jt)
          acc1[m][jt] = MFMA16(af[m], bx[jt], acc1[m][jt]);
    }
#pragma unroll
    for (int jt = 0; jt < 4; ++jt) {
      const int lcol = 64 * w + jt * 16 + l16;
      const int piece = 4 * w + jt;
#pragma unroll
      for (int m = 0; m < 4; ++m)
#pragma unroll
        for (int r = 0; r < 4; ++r) {
          const int row = 16 * m + quad * 4 + r;
          const int grow = row0 + row;
          float av;
          if (bits_in) {
            const unsigned short m16 = ((const unsigned short*)bits_s)[row * 32 + piece];
            av = (float)((m16 >> l16) & 1);
          } else {
            av = __builtin_nontemporal_load(
                adj + ((size_t)b * N_ + grow) * N_ + lcol);
          }
          const bool diag = (grow == lcol);
          if (bits_out) {
            const unsigned long long bal = __ballot(diag || av != 0.0f);
            if (l16 == 0)
              bits_out[((size_t)b * N_ + row0 + 16 * m + 4 * quad + r) * 32 + piece] =
                  (unsigned short)((bal >> (quad * 16)) & 0xFFFFull);
          }
          const float sg = sigmoidf_(acc1[m][jt][r]);
          const float v = diag ? (sg + 1e-5f) : sg * av;
          const bf16 bv = (bf16)v;
          xps[row * 520 + lcol] = bv;
          p[m][r] += (float)bv;
        }
    }
  }
  // T14-deep: p3's first-half B-stream (ks 0..7) issues here (acc1 dead);
  // crosses b2/b3/p2 under the reduce + normalize + attls store burst.
#pragma unroll
  for (int ks = 0; ks < 8; ++ks)
#pragma unroll
    for (int i = 0; i < 2; ++i)
      btp[ks][i] = Xtp[UIDX((2 * w + i) * 16 + ks)];
  __builtin_amdgcn_sched_barrier(0);

#pragma unroll
  for (int m = 0; m < 4; ++m)
#pragma unroll
    for (int r = 0; r < 4; ++r) {
#pragma unroll
      for (int msk = 1; msk < 16; msk <<= 1) p[m][r] += __shfl_xor(p[m][r], msk, 64);
    }
  if (l16 == 0) {
#pragma unroll
    for (int m = 0; m < 4; ++m)
#pragma unroll
      for (int r = 0; r < 4; ++r) psum[w][16 * m + quad * 4 + r] = p[m][r];
  }
  BARSYNC();   // b2
  if (tid < 64) {
    float s = 0.0f;
#pragma unroll
    for (int ww = 0; ww < 8; ++ww) s += psum[ww][tid];
    rinvs[tid] = 1.0f / s;
  }
  BARSYNC();   // b3

  // ---- p2: normalize; attls f32 NT out (stays in flight); bf16 to xps ----
  const size_t abase = ((size_t)b * N_ + row0) * N_;
#pragma unroll
  for (int e = 0; e < 16; ++e) {
    const int idx = tid + e * 512;
    const int row = idx >> 7, c4 = (idx & 127) * 4;
    const float ri = rinvs[row];
    bf16x4 pv = *(const bf16x4*)&xps[row * 520 + c4];
    f32x4 nv;
    nv[0] = (float)pv[0] * ri; nv[1] = (float)pv[1] * ri;
    nv[2] = (float)pv[2] * ri; nv[3] = (float)pv[3] * ri;
    __builtin_nontemporal_store(nv, (f32x4*)(outA + abase + (size_t)row * N_ + c4));
    bf16x4 o;
    o[0] = (bf16)nv[0]; o[1] = (bf16)nv[1]; o[2] = (bf16)nv[2]; o[3] = (bf16)nv[3];
    *(bf16x4*)&xps[row * 520 + c4] = o;
  }
  BARSYNC();   // b4: attls stores NOT drained here (lgkm only)

  // ---- p3: x' = P @ x (B = xTpk; first half prefetched), K = 512 -> qs ----
  {
    f32x4 acc3[4][2] = {};
#pragma unroll
    for (int ks = 0; ks < 16; ++ks) {
      bf16x8 af[4];
#pragma unroll
      for (int m = 0; m < 4; ++m)
        af[m] = *(const bf16x8*)&xps[(16 * m + l16) * 520 + ks * 32 + quad * 8];
      bf16x8 bt[2];
#pragma unroll
      for (int i = 0; i < 2; ++i)
        bt[i] = (ks < 8) ? btp[ks][i] : Xtp[UIDX((2 * w + i) * 16 + ks)];
#pragma unroll
      for (int m = 0; m < 4; ++m)
#pragma unroll
        for (int i = 0; i < 2; ++i) acc3[m][i] = MFMA16(af[m], bt[i], acc3[m][i]);
    }
    // T14: W0 fragment loads fly across b5, consumed in p4
    bf16x8 w0r[16];
#pragma unroll
    for (int j = 0; j < 16; ++j)
      w0r[j] = W08[UIDX((2 * w + (j >> 3)) * 8 + (j & 7))];
    __builtin_amdgcn_sched_barrier(0);
#pragma unroll
    for (int m = 0; m < 4; ++m)
#pragma unroll
      for (int i = 0; i < 2; ++i) {
        const int d = 32 * w + 16 * i + l16;
#pragma unroll
        for (int r = 0; r < 4; ++r)
          qs[(16 * m + quad * 4 + r) * 264 + d] = (bf16)acc3[m][i][r];
      }
    BARSYNC();   // b5: x' in qs

    // ---- p4: h = relu(x' @ W0^T + b0) -> xps (stride 264) ----
    f32x4 acc[4][2] = {};
#pragma unroll
    for (int ks = 0; ks < 8; ++ks) {
      bf16x8 af[4];
#pragma unroll
      for (int m = 0; m < 4; ++m)
        af[m] = *(const bf16x8*)&qs[(16 * m + l16) * 264 + ks * 32 + quad * 8];
#pragma unroll
      for (int m = 0; m < 4; ++m)
#pragma unroll
        for (int i = 0; i < 2; ++i)
          acc[m][i] = MFMA16(af[m], w0r[i * 8 + ks], acc[m][i]);
    }
    // T14: W1 + residual loads fly across b6, consumed in p5
    bf16x8 w1r[16];
#pragma unroll
    for (int j = 0; j < 16; ++j)
      w1r[j] = W18[UIDX((2 * w + (j >> 3)) * 8 + (j & 7))];
    bf16x8 resid[4];
#pragma unroll
    for (int j = 0; j < 4; ++j) {
      const int uu = w * 4 + j;
      resid[j] = Xbp[UIDX(((row0 >> 4) + (uu >> 3)) * 8 + (uu & 7))];
    }
    __builtin_amdgcn_sched_barrier(0);
#pragma unroll
    for (int m = 0; m < 4; ++m)
#pragma unroll
      for (int i = 0; i < 2; ++i) {
        const int col = 32 * w + 16 * i + l16;
        const float bv = b0[col];
#pragma unroll
        for (int r = 0; r < 4; ++r)
          xps[(16 * m + quad * 4 + r) * 264 + col] = (bf16)fmaxf(acc[m][i][r] + bv, 0.0f);
      }
    BARSYNC();   // b6: h in xps; qs (x') dead

    // ---- p5: x = relu(h @ W1^T + b1) + resid; emit packed outputs ----
    // stage residual strip (regs -> LDS, loads already in flight)
#pragma unroll
    for (int j = 0; j < 4; ++j) {
      const int uu = w * 4 + j;
      const int rr = uu >> 3, kc = uu & 7;
      *(bf16x8*)&qs[(rr * 16 + l16) * 264 + kc * 32 + quad * 8] = resid[j];
    }
    f32x4 acc5[4][2] = {};
#pragma unroll
    for (int ks = 0; ks < 8; ++ks) {
      bf16x8 af[4];
#pragma unroll
      for (int m = 0; m < 4; ++m)
        af[m] = *(const bf16x8*)&xps[(16 * m + l16) * 264 + ks * 32 + quad * 8];
#pragma unroll
      for (int m = 0; m < 4; ++m)
#pragma unroll
        for (int i = 0; i < 2; ++i)
          acc5[m][i] = MFMA16(af[m], w1r[i * 8 + ks], acc5[m][i]);
    }
    BARSYNC();   // b7: resid writes visible to all

#pragma unroll
    for (int m = 0; m < 4; ++m)
#pragma unroll
      for (int i = 0; i < 2; ++i) {
        const int d = 32 * w + 16 * i + l16;
        const float bv = b1[d];
#pragma unroll
        for (int r = 0; r < 4; ++r) {
          const int nl = 16 * m + quad * 4 + r;
          const float x0 = (float)qs[nl * 264 + d];
          const float t2 = fmaxf(acc5[m][i][r] + bv, 0.0f) + x0;
          qs[nl * 264 + d] = (bf16)t2;   // own cell after b7: no race
        }
      }
    BARSYNC();   // b8: output strip staged in qs [64][264]

    // packed xb_out: 32 units, dense 1KB stores
#pragma unroll
    for (int j = 0; j < 4; ++j) {
      const int uu = w * 4 + j;
      const int rr = uu >> 3, kc = uu & 7;
      const bf16x8 v = *(const bf16x8*)&qs[(rr * 16 + l16) * 264 + kc * 32 + quad * 8];
      XbpO[UIDX(((row0 >> 4) + rr) * 8 + kc)] = v;
    }
    // packed xT_out: 32 units (LDS transpose reads), dense 1KB stores
#pragma unroll
    for (int j = 0; j < 4; ++j) {
      const int uu = w * 4 + j;
      const int d16 = uu >> 1, nk = uu & 1;
      const int d = d16 * 16 + l16;
      bf16x8 v;
#pragma unroll
      for (int e = 0; e < 8; ++e)
        v[e] = qs[(nk * 32 + quad * 8 + e) * 264 + d];
      XtpO[UIDX(d16 * 16 + (row0 >> 5) + nk)] = v;
    }
  }
}

// ---------------------------------------------------------------------------
// final_proj: out = x @ Wf^T + bf (f32). A from packed xb (dense), no LDS.
// ---------------------------------------------------------------------------
__global__ __launch_bounds__(256, 4) void final_proj(
    const bf16* __restrict__ xbpk, const bf16* __restrict__ Wfp,
    const float* __restrict__ bfv, float* __restrict__ outX)
{
  const int tid = threadIdx.x, w = tid >> 6, lane = tid & 63;
  const int l16 = lane & 15, quad = lane >> 4;
  const int wg = blockIdx.x;
  const int lid = (wg & 7) * 128 + (wg >> 3);
  const int row0g = lid * 32;
  const int b = row0g >> 9, n0 = row0g & 511;
  const bf16x8* Xbp = (const bf16x8*)xbpk + (size_t)b * 16384;
  const bf16x8* Wf8 = (const bf16x8*)Wfp;
  f32x4 acc[2][4] = {};
#pragma unroll
  for (int ks = 0; ks < 8; ++ks) {
    bf16x8 af[2];
#pragma unroll
    for (int m = 0; m < 2; ++m)
      af[m] = Xbp[UIDX(((n0 >> 4) + m) * 8 + ks)];
    bf16x8 bw[4];
#pragma unroll
    for (int i = 0; i < 4; ++i)
      bw[i] = Wf8[UIDX((4 * w + i) * 8 + ks)];
#pragma unroll
    for (int m = 0; m < 2; ++m)
#pragma unroll
      for (int i = 0; i < 4; ++i) acc[m][i] = MFMA16(af[m], bw[i], acc[m][i]);
  }
#pragma unroll
  for (int m = 0; m < 2; ++m)
#pragma unroll
    for (int i = 0; i < 4; ++i) {
      const int col = 64 * w + 16 * i + l16;
      const float bv = bfv[col];
#pragma unroll
      for (int r = 0; r < 4; ++r) {
        const size_t R = (size_t)row0g + 16 * m + quad * 4 + r;
        __builtin_nontemporal_store(acc[m][i][r] + bv, outX + R * D_ + col);
      }
    }
}

extern "C" void kernel_launch(void* const* d_in, const int* in_sizes, int n_in,
                              void* d_out, int out_size, void* d_ws, size_t ws_size,
                              hipStream_t stream)
{
  const float* x_in  = (const float*)d_in[0];
  const float* adj   = (const float*)d_in[1];
  const float* wattn = (const float*)d_in[2];
  const float* battn = (const float*)d_in[3];
  const float* w0    = (const float*)d_in[4];
  const float* b0    = (const float*)d_in[5];
  const float* w1    = (const float*)d_in[6];
  const float* b1    = (const float*)d_in[7];
  const float* wf    = (const float*)d_in[8];
  const float* bfin  = (const float*)d_in[9];

  float* out_x    = (float*)d_out;                     // [B,N,D] f32
  float* out_attn = out_x + (size_t)B_ * N_ * D_;      // [L,B,N,N]

  const size_t XBN = (size_t)B_ * N_ * D_;
  const int DD2 = D_ * D_;
  bf16* wb   = (bf16*)d_ws;                            // 13*D*D packed weights
  bf16* xbp0 = wb + 13 * DD2;
  bf16* xtp0 = xbp0 + XBN;
  bf16* xbp1 = xtp0 + XBN;
  bf16* xtp1 = xbp1 + XBN;
  unsigned short* bits = (unsigned short*)(xtp1 + XBN);// [B,N,32] uint16

  // pack weights (f32 -> packed bf16 fragments)
  pack_w<<<dim3(4 * 32), 256, 0, stream>>>(wattn, wb);
  pack_w<<<dim3(4 * 32), 256, 0, stream>>>(w0, wb + 4 * DD2);
  pack_w<<<dim3(4 * 32), 256, 0, stream>>>(w1, wb + 8 * DD2);
  pack_w<<<dim3(1 * 32), 256, 0, stream>>>(wf, wb + 12 * DD2);

  // x -> packed xb + packed xT
  init_pack<<<dim3(8192), 256, 0, stream>>>(x_in, xbp0, xtp0);

  bf16* xbps[2] = {xbp0, xbp1};
  bf16* xtps[2] = {xtp0, xtp1};
  for (int l = 0; l < L_; ++l) {
    const int pi = l & 1, po = 1 - pi;
    gat_layer<<<dim3((N_ / 64) * B_), 512, 0, stream>>>(
        xbps[pi], xtps[pi], xbps[po], xtps[po],
        wb + l * DD2, battn + l * D_,
        wb + (4 + l) * DD2, b0 + l * D_,
        wb + (8 + l) * DD2, b1 + l * D_,
        adj, (l == 0) ? nullptr : bits, (l == 0) ? bits : nullptr,
        out_attn + (size_t)l * B_ * N_ * N_);
  }
  final_proj<<<dim3((B_ * N_) / 32), 256, 0, stream>>>(
      xbps[0], wb + 12 * DD2, bfin, out_x);
}